// Round 4
// baseline (53.380 us; speedup 1.0000x reference)
//
#include <hip/hip_runtime.h>
#include <cstdint>

typedef unsigned short u16;
typedef unsigned int u32;
typedef __bf16 bf16x8 __attribute__((ext_vector_type(8)));
typedef float f32x4 __attribute__((ext_vector_type(4)));

#define N_ROWS 4096
#define D_COLS 512

__device__ __forceinline__ u16 f2bf(float f) {
    u32 u = __float_as_uint(f);
    u += 0x7fffu + ((u >> 16) & 1u);
    return (u16)(u >> 16);
}

#define GLDS(g, l)                                                            \
    __builtin_amdgcn_global_load_lds(                                         \
        (const __attribute__((address_space(1))) void*)(g),                   \
        (__attribute__((address_space(3))) void*)(l), 16, 0, 0)

// ---------------- kernel 1: convert + row norms + partial column sums -------
__global__ __launch_bounds__(256) void k_prep(const float* __restrict__ X,
                                              u16* __restrict__ Xb,
                                              float* __restrict__ sq,
                                              float* __restrict__ partial) {
    __shared__ float cs[4][512];
    const int tid = threadIdx.x;
    const int w = tid >> 6, l = tid & 63;
    const int row0 = blockIdx.x * 16 + w * 4;
    float csum[8] = {0.f,0.f,0.f,0.f,0.f,0.f,0.f,0.f};
#pragma unroll
    for (int r = 0; r < 4; ++r) {
        const int row = row0 + r;
        const float4* src = (const float4*)(X + (size_t)row * D_COLS);
        float4 f0 = src[l * 2];
        float4 f1 = src[l * 2 + 1];
        float v[8] = {f0.x, f0.y, f0.z, f0.w, f1.x, f1.y, f1.z, f1.w};
        float ss = 0.f;
#pragma unroll
        for (int j = 0; j < 8; ++j) { ss += v[j] * v[j]; csum[j] += v[j]; }
        uint4 st;
        st.x = (u32)f2bf(v[0]) | ((u32)f2bf(v[1]) << 16);
        st.y = (u32)f2bf(v[2]) | ((u32)f2bf(v[3]) << 16);
        st.z = (u32)f2bf(v[4]) | ((u32)f2bf(v[5]) << 16);
        st.w = (u32)f2bf(v[6]) | ((u32)f2bf(v[7]) << 16);
        *(uint4*)(Xb + (size_t)row * D_COLS + l * 8) = st;
#pragma unroll
        for (int m = 32; m > 0; m >>= 1) ss += __shfl_xor(ss, m, 64);
        if (l == 0) sq[row] = ss;
    }
#pragma unroll
    for (int j = 0; j < 8; ++j) cs[w][l * 8 + j] = csum[j];
    __syncthreads();
    for (int d = tid; d < 512; d += 256)
        partial[blockIdx.x * 512 + d] = cs[0][d] + cs[1][d] + cs[2][d] + cs[3][d];
}

// ---------------- kernel 2: S1/S2 partials, 8 blocks ------------------------
__global__ __launch_bounds__(256) void k_sigma(const float* __restrict__ sq,
                                               const float* __restrict__ partial,
                                               float* __restrict__ parts) {
    __shared__ float csm[4][64];
    __shared__ float red[8];
    const int g = blockIdx.x;
    const int t = threadIdx.x;
    const int c = g * 64 + (t & 63);
    const int ch = t >> 6;
    float cssum = 0.f;
#pragma unroll 8
    for (int b = ch * 64; b < ch * 64 + 64; ++b) cssum += partial[b * 512 + c];
    csm[ch][t & 63] = cssum;
    float s1 = sq[g * 512 + t] + sq[g * 512 + 256 + t];
    __syncthreads();
    float s2 = 0.f;
    if (t < 64) {
        float v = csm[0][t] + csm[1][t] + csm[2][t] + csm[3][t];
        s2 = v * v;
    }
#pragma unroll
    for (int m = 32; m > 0; m >>= 1) {
        s1 += __shfl_xor(s1, m, 64);
        s2 += __shfl_xor(s2, m, 64);
    }
    if ((t & 63) == 0) { red[ch] = s1; red[4 + ch] = s2; }
    __syncthreads();
    if (t == 0) {
        parts[g] = red[0] + red[1] + red[2] + red[3];
        parts[8 + g] = red[4];
    }
}

// ---------------- kernel 3: 128x128 GEMM, 3-buf counted-vmcnt, 3 blk/CU -----
// 4 waves (2x2), wave tile 64x64, BK=32, 16 K-tiles, nt-store fused exp.
__global__ __launch_bounds__(256, 3) void k_gemm(const u16* __restrict__ Xb,
                                                 const float* __restrict__ sq,
                                                 const float* __restrict__ parts,
                                                 float* __restrict__ out) {
    __shared__ __align__(16) u16 As[3][128 * 32];   // 8 KB each
    __shared__ __align__(16) u16 Bs[3][128 * 32];
    __shared__ float sqA[128], sqB[128];
    __shared__ float c_sh;

    const int tid = threadIdx.x;
    const int lane = tid & 63;
    const int wid = tid >> 6;
    const int wr = wid >> 1, wc = wid & 1;          // 2x2 waves, 64x64 each

    // T1: XCD swizzle — each XCD owns a 16(by) x 8(bx) rect of the 32x32 grid
    const int bid = blockIdx.x;                      // 0..1023
    const int xcd = bid & 7, rr = bid >> 3;          // rr 0..127
    const int by = (xcd >> 2) * 16 + (rr & 15);
    const int bx = (xcd & 3) * 8 + (rr >> 4);
    const int i0 = by * 128, j0 = bx * 128;

    if (tid < 128) sqA[tid] = sq[i0 + tid];
    else           sqB[tid - 128] = sq[j0 + tid - 128];
    if (tid == 0) {
        float S1 = 0.f, S2 = 0.f;
#pragma unroll
        for (int i = 0; i < 8; ++i) { S1 += parts[i]; S2 += parts[8 + i]; }
        const float mean_d2 = 2.f * S1 / (float)N_ROWS
                            - 2.f * S2 / ((float)N_ROWS * (float)N_ROWS);
        c_sh = -1.4426950408889634f / (2.f * mean_d2);   // ALPHA=1
    }

    // staging: 4 GLDS/thread/K-tile (A rows sr,sr+64; B rows sr,sr+64)
    // swizzle: slot ^ ((row>>1)&3)  -> 2-way bank aliasing only (free)
    const int sr = tid >> 2;                         // 0..63
    const int sby = (tid & 3) * 16;
    const int sw0 = sby ^ (((sr >> 1) & 3) << 4);
    const int sw1 = sby ^ ((((sr + 64) >> 1) & 3) << 4);
    const char* xb = (const char*)Xb;
    const char* gA0 = xb + (size_t)(i0 + sr) * 1024 + sw0;
    const char* gA1 = xb + (size_t)(i0 + sr + 64) * 1024 + sw1;
    const char* gB0 = xb + (size_t)(j0 + sr) * 1024 + sw0;
    const char* gB1 = xb + (size_t)(j0 + sr + 64) * 1024 + sw1;

#define STAGE(buf, kt)                                                        \
    do {                                                                      \
        GLDS(gA0 + (kt) * 64, (char*)As[buf] + tid * 16);                     \
        GLDS(gA1 + (kt) * 64, (char*)As[buf] + 4096 + tid * 16);              \
        GLDS(gB0 + (kt) * 64, (char*)Bs[buf] + tid * 16);                     \
        GLDS(gB1 + (kt) * 64, (char*)Bs[buf] + 4096 + tid * 16);              \
    } while (0)

    f32x4 acc[4][4];
#pragma unroll
    for (int m = 0; m < 4; ++m)
#pragma unroll
        for (int n = 0; n < 4; ++n) acc[m][n] = (f32x4){0.f, 0.f, 0.f, 0.f};

    const int frow = lane & 15;
    const int klane = lane >> 4;

    STAGE(0, 0);
    STAGE(1, 1);

    int cb = 0, nb = 2;
    for (int kt = 0; kt < 16; ++kt) {
        if (kt < 15) asm volatile("s_waitcnt vmcnt(4)" ::: "memory");
        else         asm volatile("s_waitcnt vmcnt(0)" ::: "memory");
        asm volatile("s_barrier" ::: "memory");
        if (kt + 2 < 16) STAGE(nb, kt + 2);
        const char* Ab = (const char*)As[cb];
        const char* Bb = (const char*)Bs[cb];
        bf16x8 a[4], b[4];
#pragma unroll
        for (int m = 0; m < 4; ++m) {
            const int row = wr * 64 + m * 16 + frow;
            a[m] = *(const bf16x8*)(Ab + row * 64 +
                                    ((klane * 16) ^ (((row >> 1) & 3) << 4)));
        }
#pragma unroll
        for (int n = 0; n < 4; ++n) {
            const int row = wc * 64 + n * 16 + frow;
            b[n] = *(const bf16x8*)(Bb + row * 64 +
                                    ((klane * 16) ^ (((row >> 1) & 3) << 4)));
        }
        __builtin_amdgcn_s_setprio(1);
#pragma unroll
        for (int m = 0; m < 4; ++m)
#pragma unroll
            for (int n = 0; n < 4; ++n)
                acc[m][n] = __builtin_amdgcn_mfma_f32_16x16x32_bf16(
                    a[m], b[n], acc[m][n], 0, 0, 0);
        __builtin_amdgcn_s_setprio(0);
        cb = (cb == 2) ? 0 : cb + 1;
        nb = (nb == 2) ? 0 : nb + 1;
    }
#undef STAGE

    // epilogue: d2 = sqA + sqB - 2*dot ; out = exp2(c*d2), nontemporal
    const float cval = c_sh;
    const int q = lane >> 4;
#pragma unroll
    for (int m = 0; m < 4; ++m) {
#pragma unroll
        for (int n = 0; n < 4; ++n) {
            const int col = wc * 64 + n * 16 + frow;
            const float sb = sqB[col];
#pragma unroll
            for (int r = 0; r < 4; ++r) {
                const int row = wr * 64 + m * 16 + q * 4 + r;
                const float d2 = sqA[row] + sb - 2.0f * acc[m][n][r];
                __builtin_nontemporal_store(
                    exp2f(cval * d2),
                    &out[(size_t)(i0 + row) * N_ROWS + (j0 + col)]);
            }
        }
    }
}

extern "C" void kernel_launch(void* const* d_in, const int* in_sizes, int n_in,
                              void* d_out, int out_size, void* d_ws, size_t ws_size,
                              hipStream_t stream) {
    const float* X = (const float*)d_in[0];
    float* out = (float*)d_out;
    char* ws = (char*)d_ws;

    u16*   Xb   = (u16*)ws;                                   // 4 MB
    float* part = (float*)(ws + (4u << 20));                  // 512 KB
    float* sq   = (float*)(ws + (4u << 20) + (512u << 10));   // 16 KB
    float* prt  = (float*)(ws + (4u << 20) + (512u << 10) + (16u << 10));

    hipLaunchKernelGGL(k_prep, dim3(256), dim3(256), 0, stream, X, Xb, sq, part);
    hipLaunchKernelGGL(k_sigma, dim3(8), dim3(256), 0, stream, sq, part, prt);
    hipLaunchKernelGGL(k_gemm, dim3(1024), dim3(256), 0, stream, Xb, sq, prt, out);
}

// Round 5
// 46.451 us; speedup vs baseline: 1.1492x; 1.1492x over previous
//
#include <hip/hip_runtime.h>
#include <cstdint>

typedef unsigned short u16;
typedef unsigned int u32;
typedef __bf16 bf16x8 __attribute__((ext_vector_type(8)));
typedef float f32x4 __attribute__((ext_vector_type(4)));

#define N_ROWS 4096
#define D_COLS 512

__device__ __forceinline__ u16 f2bf(float f) {
    u32 u = __float_as_uint(f);
    u += 0x7fffu + ((u >> 16) & 1u);
    return (u16)(u >> 16);
}

#define GLDS(g, l)                                                            \
    __builtin_amdgcn_global_load_lds(                                         \
        (const __attribute__((address_space(1))) void*)(g),                   \
        (__attribute__((address_space(3))) void*)(l), 16, 0, 0)

// ---------------- kernel 1: convert + row norms + partial column sums -------
__global__ __launch_bounds__(256) void k_prep(const float* __restrict__ X,
                                              u16* __restrict__ Xb,
                                              float* __restrict__ sq,
                                              float* __restrict__ partial) {
    __shared__ float cs[4][512];
    const int tid = threadIdx.x;
    const int w = tid >> 6, l = tid & 63;
    const int row0 = blockIdx.x * 16 + w * 4;
    float csum[8] = {0.f,0.f,0.f,0.f,0.f,0.f,0.f,0.f};
#pragma unroll
    for (int r = 0; r < 4; ++r) {
        const int row = row0 + r;
        const float4* src = (const float4*)(X + (size_t)row * D_COLS);
        float4 f0 = src[l * 2];
        float4 f1 = src[l * 2 + 1];
        float v[8] = {f0.x, f0.y, f0.z, f0.w, f1.x, f1.y, f1.z, f1.w};
        float ss = 0.f;
#pragma unroll
        for (int j = 0; j < 8; ++j) { ss += v[j] * v[j]; csum[j] += v[j]; }
        uint4 st;
        st.x = (u32)f2bf(v[0]) | ((u32)f2bf(v[1]) << 16);
        st.y = (u32)f2bf(v[2]) | ((u32)f2bf(v[3]) << 16);
        st.z = (u32)f2bf(v[4]) | ((u32)f2bf(v[5]) << 16);
        st.w = (u32)f2bf(v[6]) | ((u32)f2bf(v[7]) << 16);
        *(uint4*)(Xb + (size_t)row * D_COLS + l * 8) = st;
#pragma unroll
        for (int m = 32; m > 0; m >>= 1) ss += __shfl_xor(ss, m, 64);
        if (l == 0) sq[row] = ss;
    }
#pragma unroll
    for (int j = 0; j < 8; ++j) cs[w][l * 8 + j] = csum[j];
    __syncthreads();
    for (int d = tid; d < 512; d += 256)
        partial[blockIdx.x * 512 + d] = cs[0][d] + cs[1][d] + cs[2][d] + cs[3][d];
}

// ---------------- kernel 2: S1/S2 partials, 8 blocks ------------------------
__global__ __launch_bounds__(256) void k_sigma(const float* __restrict__ sq,
                                               const float* __restrict__ partial,
                                               float* __restrict__ parts) {
    __shared__ float csm[4][64];
    __shared__ float red[8];
    const int g = blockIdx.x;
    const int t = threadIdx.x;
    const int c = g * 64 + (t & 63);
    const int ch = t >> 6;
    float cssum = 0.f;
#pragma unroll 8
    for (int b = ch * 64; b < ch * 64 + 64; ++b) cssum += partial[b * 512 + c];
    csm[ch][t & 63] = cssum;
    float s1 = sq[g * 512 + t] + sq[g * 512 + 256 + t];
    __syncthreads();
    float s2 = 0.f;
    if (t < 64) {
        float v = csm[0][t] + csm[1][t] + csm[2][t] + csm[3][t];
        s2 = v * v;
    }
#pragma unroll
    for (int m = 32; m > 0; m >>= 1) {
        s1 += __shfl_xor(s1, m, 64);
        s2 += __shfl_xor(s2, m, 64);
    }
    if ((t & 63) == 0) { red[ch] = s1; red[4 + ch] = s2; }
    __syncthreads();
    if (t == 0) {
        parts[g] = red[0] + red[1] + red[2] + red[3];
        parts[8 + g] = red[4];
    }
}

// ---------------- kernel 3: 256x256 GEMM, 8-phase schedule (T2+T3+T4+T5) ----
// 8 waves (2Mx4N), BK=64 (8 K-tiles), dbuf 128KB LDS, fused exp epilogue.
#define BAR __builtin_amdgcn_s_barrier()
#define LGKM0 do { asm volatile("s_waitcnt lgkmcnt(0)" ::: "memory");         \
                   __builtin_amdgcn_sched_barrier(0); } while (0)
#define PRIO1 __builtin_amdgcn_s_setprio(1)
#define PRIO0 __builtin_amdgcn_s_setprio(0)

__global__ __launch_bounds__(512, 2) void k_gemm(const u16* __restrict__ Xb,
                                                 const float* __restrict__ sq,
                                                 const float* __restrict__ parts,
                                                 float* __restrict__ out) {
    __shared__ __align__(16) u16 As[2][256 * 64];   // 32 KB each
    __shared__ __align__(16) u16 Bs[2][256 * 64];
    __shared__ float sqA[256], sqB[256];
    __shared__ float c_sh;

    const int tid = threadIdx.x;
    const int lane = tid & 63;
    const int wid = tid >> 6;
    const int wr = wid >> 2, wc = wid & 3;          // 2M x 4N waves

    // T1: XCD swizzle — each XCD owns an 8(by) x 4(bx) rect of the 16x16 grid
    const int bid = blockIdx.x;                      // 0..255
    const int xcd = bid & 7, rr = bid >> 3;          // rr 0..31
    const int by = (xcd >> 2) * 8 + (rr & 7);
    const int bx = (xcd & 3) * 4 + (rr >> 3);
    const int i0 = by * 256, j0 = bx * 256;

    if (tid < 256) sqA[tid] = sq[i0 + tid];
    else           sqB[tid - 256] = sq[j0 + tid - 256];
    if (tid == 0) {
        float S1 = 0.f, S2 = 0.f;
#pragma unroll
        for (int i = 0; i < 8; ++i) { S1 += parts[i]; S2 += parts[8 + i]; }
        const float mean_d2 = 2.f * S1 / (float)N_ROWS
                            - 2.f * S2 / ((float)N_ROWS * (float)N_ROWS);
        c_sh = -1.4426950408889634f / (2.f * mean_d2);   // ALPHA=1
    }
    __syncthreads();   // sqA/sqB/c_sh visible; NO GLDS issued yet

    // staging map: sweep s covers 64 rows; thread t -> row (t>>3), slot (t&7).
    // T2 swizzle: 16B slot ^= (row&7), pre-applied on the GLOBAL source
    // (LDS dest stays linear), and re-applied on ds_read. Rows are 128B.
    const int strow = tid >> 3;                      // 0..63
    const int sslot = (tid & 7) ^ (strow & 7);
    const char* xb = (const char*)Xb;
    const char* gA = xb + (size_t)(i0 + strow) * 1024 + sslot * 16;
    const char* gB = xb + (size_t)(j0 + strow) * 1024 + sslot * 16;
    // sweep s: + s*65536 (64 rows); K-tile kt: + kt*128

    f32x4 acc[8][4];
#pragma unroll
    for (int m = 0; m < 8; ++m)
#pragma unroll
        for (int n = 0; n < 4; ++n) acc[m][n] = (f32x4){0.f, 0.f, 0.f, 0.f};

    const int frow = lane & 15;
    const int klane = lane >> 4;
    const int aoff0 = ((klane ^ (frow & 7)) << 4);   // read-side swizzled slot

    // prologue: stage tile 0 (order: B0..B3, A0, A2, A1, A3 — A1/A3 last)
    {
        char* A0 = (char*)As[0]; char* B0 = (char*)Bs[0];
        GLDS(gB,               B0 + tid * 16);
        GLDS(gB + 1 * 65536,   B0 + 1 * 8192 + tid * 16);
        GLDS(gB + 2 * 65536,   B0 + 2 * 8192 + tid * 16);
        GLDS(gB + 3 * 65536,   B0 + 3 * 8192 + tid * 16);
        GLDS(gA,               A0 + tid * 16);
        GLDS(gA + 2 * 65536,   A0 + 2 * 8192 + tid * 16);
        GLDS(gA + 1 * 65536,   A0 + 1 * 8192 + tid * 16);
        GLDS(gA + 3 * 65536,   A0 + 3 * 8192 + tid * 16);
    }
    asm volatile("s_waitcnt vmcnt(2)" ::: "memory");  // B*,A0,A2 landed
    BAR;

#define READ_A(mh, ks)                                                        \
    do {                                                                      \
        _Pragma("unroll")                                                     \
        for (int i = 0; i < 4; ++i)                                           \
            a[i] = *(const bf16x8*)(Ab +                                      \
                (wr * 128 + (mh) * 64 + i * 16 + frow) * 128 +                \
                (aoff0 ^ ((ks) * 64)));                                       \
    } while (0)
#define READ_B(ks)                                                            \
    do {                                                                      \
        _Pragma("unroll")                                                     \
        for (int n = 0; n < 4; ++n)                                           \
            b[n] = *(const bf16x8*)(Bb +                                      \
                (wc * 64 + n * 16 + frow) * 128 +                             \
                (aoff0 ^ ((ks) * 64)));                                       \
    } while (0)
#define MFMA_PH(mh)                                                           \
    do {                                                                      \
        _Pragma("unroll")                                                     \
        for (int i = 0; i < 4; ++i)                                           \
            _Pragma("unroll")                                                 \
            for (int n = 0; n < 4; ++n)                                       \
                acc[(mh) * 4 + i][n] = __builtin_amdgcn_mfma_f32_16x16x32_bf16( \
                    a[i], b[n], acc[(mh) * 4 + i][n], 0, 0, 0);               \
    } while (0)

    for (int kt = 0; kt < 8; ++kt) {
        const int buf = kt & 1;
        const char* Ab = (const char*)As[buf];
        const char* Bb = (const char*)Bs[buf];
        char* AsN = (char*)As[buf ^ 1];
        char* BsN = (char*)Bs[buf ^ 1];
        const bool st = kt < 7;
        const int koff = (kt + 1) * 128;
        bf16x8 a[4], b[4];

        // ---- phase 0: (mh0, ks0); stage next B0,B1
        READ_A(0, 0); READ_B(0);
        if (st) {
            GLDS(gB + koff,             BsN + tid * 16);
            GLDS(gB + 1 * 65536 + koff, BsN + 1 * 8192 + tid * 16);
        }
        BAR; LGKM0; PRIO1; MFMA_PH(0); PRIO0;
        if (st) asm volatile("s_waitcnt vmcnt(2)" ::: "memory"); // A1,A3(kt) in
        else    asm volatile("s_waitcnt vmcnt(0)" ::: "memory"); // last tile
        BAR;
        // ---- phase 1: (mh1, ks0); stage next B2,B3
        READ_A(1, 0);
        if (st) {
            GLDS(gB + 2 * 65536 + koff, BsN + 2 * 8192 + tid * 16);
            GLDS(gB + 3 * 65536 + koff, BsN + 3 * 8192 + tid * 16);
        }
        BAR; LGKM0; PRIO1; MFMA_PH(1); PRIO0; BAR;
        // ---- phase 2: (mh0, ks1); stage next A0,A2
        READ_A(0, 1); READ_B(1);
        if (st) {
            GLDS(gA + koff,             AsN + tid * 16);
            GLDS(gA + 2 * 65536 + koff, AsN + 2 * 8192 + tid * 16);
        }
        BAR; LGKM0; PRIO1; MFMA_PH(0); PRIO0; BAR;
        // ---- phase 3: (mh1, ks1); stage next A1,A3
        READ_A(1, 1);
        if (st) {
            GLDS(gA + 1 * 65536 + koff, AsN + 1 * 8192 + tid * 16);
            GLDS(gA + 3 * 65536 + koff, AsN + 3 * 8192 + tid * 16);
        }
        BAR; LGKM0; PRIO1; MFMA_PH(1); PRIO0;
        if (st) asm volatile("s_waitcnt vmcnt(2)" ::: "memory"); // 6 oldest in
        BAR;
    }
#undef READ_A
#undef READ_B
#undef MFMA_PH

    // ---- epilogue: d2 = sqA + sqB - 2*dot ; out = exp2(c*d2) ----
    const float cval = c_sh;
    const int q = lane >> 4;
#pragma unroll
    for (int m = 0; m < 8; ++m) {
#pragma unroll
        for (int n = 0; n < 4; ++n) {
            const int col = wc * 64 + n * 16 + frow;
            const float sb = sqB[col];
#pragma unroll
            for (int r = 0; r < 4; ++r) {
                const int row = wr * 128 + m * 16 + q * 4 + r;
                const float d2 = sqA[row] + sb - 2.0f * acc[m][n][r];
                out[(size_t)(i0 + row) * N_ROWS + (j0 + col)] = exp2f(cval * d2);
            }
        }
    }
}

extern "C" void kernel_launch(void* const* d_in, const int* in_sizes, int n_in,
                              void* d_out, int out_size, void* d_ws, size_t ws_size,
                              hipStream_t stream) {
    const float* X = (const float*)d_in[0];
    float* out = (float*)d_out;
    char* ws = (char*)d_ws;

    u16*   Xb   = (u16*)ws;                                   // 4 MB
    float* part = (float*)(ws + (4u << 20));                  // 512 KB
    float* sq   = (float*)(ws + (4u << 20) + (512u << 10));   // 16 KB
    float* prt  = (float*)(ws + (4u << 20) + (512u << 10) + (16u << 10));

    hipLaunchKernelGGL(k_prep, dim3(256), dim3(256), 0, stream, X, Xb, sq, part);
    hipLaunchKernelGGL(k_sigma, dim3(8), dim3(256), 0, stream, sq, part, prt);
    hipLaunchKernelGGL(k_gemm, dim3(256), dim3(512), 0, stream, Xb, sq, prt, out);
}

// Round 6
// 45.991 us; speedup vs baseline: 1.1607x; 1.0100x over previous
//
#include <hip/hip_runtime.h>
#include <cstdint>

typedef unsigned short u16;
typedef unsigned int u32;
typedef __bf16 bf16x8 __attribute__((ext_vector_type(8)));
typedef float f32x4 __attribute__((ext_vector_type(4)));

#define N_ROWS 4096
#define D_COLS 512

__device__ __forceinline__ u16 f2bf(float f) {
    u32 u = __float_as_uint(f);
    u += 0x7fffu + ((u >> 16) & 1u);
    return (u16)(u >> 16);
}

#define GLDS(g, l)                                                            \
    __builtin_amdgcn_global_load_lds(                                         \
        (const __attribute__((address_space(1))) void*)(g),                   \
        (__attribute__((address_space(3))) void*)(l), 16, 0, 0)

// ---------------- kernel 1: convert + row norms + partial column sums -------
__global__ __launch_bounds__(256) void k_prep(const float* __restrict__ X,
                                              u16* __restrict__ Xb,
                                              float* __restrict__ sq,
                                              float* __restrict__ partial) {
    __shared__ float cs[4][512];
    const int tid = threadIdx.x;
    const int w = tid >> 6, l = tid & 63;
    const int row0 = blockIdx.x * 16 + w * 4;
    float csum[8] = {0.f,0.f,0.f,0.f,0.f,0.f,0.f,0.f};
#pragma unroll
    for (int r = 0; r < 4; ++r) {
        const int row = row0 + r;
        const float4* src = (const float4*)(X + (size_t)row * D_COLS);
        float4 f0 = src[l * 2];
        float4 f1 = src[l * 2 + 1];
        float v[8] = {f0.x, f0.y, f0.z, f0.w, f1.x, f1.y, f1.z, f1.w};
        float ss = 0.f;
#pragma unroll
        for (int j = 0; j < 8; ++j) { ss += v[j] * v[j]; csum[j] += v[j]; }
        uint4 st;
        st.x = (u32)f2bf(v[0]) | ((u32)f2bf(v[1]) << 16);
        st.y = (u32)f2bf(v[2]) | ((u32)f2bf(v[3]) << 16);
        st.z = (u32)f2bf(v[4]) | ((u32)f2bf(v[5]) << 16);
        st.w = (u32)f2bf(v[6]) | ((u32)f2bf(v[7]) << 16);
        *(uint4*)(Xb + (size_t)row * D_COLS + l * 8) = st;
#pragma unroll
        for (int m = 32; m > 0; m >>= 1) ss += __shfl_xor(ss, m, 64);
        if (l == 0) sq[row] = ss;
    }
#pragma unroll
    for (int j = 0; j < 8; ++j) cs[w][l * 8 + j] = csum[j];
    __syncthreads();
    for (int d = tid; d < 512; d += 256)
        partial[blockIdx.x * 512 + d] = cs[0][d] + cs[1][d] + cs[2][d] + cs[3][d];
}

// ---------------- kernel 2: S1/S2 partials, 8 blocks ------------------------
__global__ __launch_bounds__(256) void k_sigma(const float* __restrict__ sq,
                                               const float* __restrict__ partial,
                                               float* __restrict__ parts) {
    __shared__ float csm[4][64];
    __shared__ float red[8];
    const int g = blockIdx.x;
    const int t = threadIdx.x;
    const int c = g * 64 + (t & 63);
    const int ch = t >> 6;
    float cssum = 0.f;
#pragma unroll 8
    for (int b = ch * 64; b < ch * 64 + 64; ++b) cssum += partial[b * 512 + c];
    csm[ch][t & 63] = cssum;
    float s1 = sq[g * 512 + t] + sq[g * 512 + 256 + t];
    __syncthreads();
    float s2 = 0.f;
    if (t < 64) {
        float v = csm[0][t] + csm[1][t] + csm[2][t] + csm[3][t];
        s2 = v * v;
    }
#pragma unroll
    for (int m = 32; m > 0; m >>= 1) {
        s1 += __shfl_xor(s1, m, 64);
        s2 += __shfl_xor(s2, m, 64);
    }
    if ((t & 63) == 0) { red[ch] = s1; red[4 + ch] = s2; }
    __syncthreads();
    if (t == 0) {
        parts[g] = red[0] + red[1] + red[2] + red[3];
        parts[8 + g] = red[4];
    }
}

// ---------------- kernel 3: 128x128 GEMM, dbuf, 2 blocks/CU TLP -------------
// 4 waves (2x2), wave tile 64x64, BK=64, 8 K-tiles, 64KB LDS, grid 1024.
__global__ __launch_bounds__(256, 2) void k_gemm(const u16* __restrict__ Xb,
                                                 const float* __restrict__ sq,
                                                 const float* __restrict__ parts,
                                                 float* __restrict__ out) {
    __shared__ __align__(16) u16 As[2][128 * 64];   // 16 KB each
    __shared__ __align__(16) u16 Bs[2][128 * 64];
    __shared__ float sqA[128], sqB[128];
    __shared__ float c_sh;

    const int tid = threadIdx.x;
    const int lane = tid & 63;
    const int wid = tid >> 6;
    const int wr = wid >> 1, wc = wid & 1;           // 2x2 waves, 64x64 each

    // T1: bijective XCD swizzle — each XCD owns an 8(by) x 16(bx) rect
    const int bid = blockIdx.x;                      // 0..1023
    const int xcd = bid & 7, rr = bid >> 3;          // rr 0..127
    const int by = (xcd >> 1) * 8 + (rr & 7);
    const int bx = (xcd & 1) * 16 + (rr >> 3);
    const int i0 = by * 128, j0 = bx * 128;

    // staging map: sweep s covers rows s*32 + (tid>>3); slot (tid&7) of 8.
    // T2 swizzle pre-applied on global source; LDS dest linear.
    const int strow = tid >> 3;                      // 0..31
    const int sslot = (tid & 7) ^ (strow & 7);       // (s*32 preserves row&7)
    const char* xb = (const char*)Xb;
    const char* gA = xb + (size_t)(i0 + strow) * 1024 + sslot * 16;
    const char* gB = xb + (size_t)(j0 + strow) * 1024 + sslot * 16;

#define STAGE(buf, kt)                                                        \
    do {                                                                      \
        _Pragma("unroll")                                                     \
        for (int s = 0; s < 4; ++s) {                                         \
            GLDS(gA + s * 32768 + (kt) * 128,                                 \
                 (char*)As[buf] + s * 4096 + tid * 16);                       \
            GLDS(gB + s * 32768 + (kt) * 128,                                 \
                 (char*)Bs[buf] + s * 4096 + tid * 16);                       \
        }                                                                     \
    } while (0)

    // prologue: stage tile 0; sq + c while loads fly
    STAGE(0, 0);
    if (tid < 128) sqA[tid] = sq[i0 + tid];
    else           sqB[tid - 128] = sq[j0 + tid - 128];
    if (tid == 0) {
        float S1 = 0.f, S2 = 0.f;
#pragma unroll
        for (int i = 0; i < 8; ++i) { S1 += parts[i]; S2 += parts[8 + i]; }
        const float mean_d2 = 2.f * S1 / (float)N_ROWS
                            - 2.f * S2 / ((float)N_ROWS * (float)N_ROWS);
        c_sh = -1.4426950408889634f / (2.f * mean_d2);   // ALPHA=1
    }

    f32x4 acc[4][4];
#pragma unroll
    for (int m = 0; m < 4; ++m)
#pragma unroll
        for (int n = 0; n < 4; ++n) acc[m][n] = (f32x4){0.f, 0.f, 0.f, 0.f};

    const int frow = lane & 15;
    const int klane = lane >> 4;
    const int s0 = (klane ^ (frow & 7)) << 4;        // read-side swizzled slot

    for (int kt = 0; kt < 8; ++kt) {
        const int buf = kt & 1;
        // implicit vmcnt(0)+lgkmcnt(0)+barrier: tile kt landed for all waves;
        // all waves done reading tile kt-1 (so buf^1 is free to overwrite)
        __syncthreads();
        if (kt < 7) STAGE(buf ^ 1, kt + 1);          // issue-early, lands
                                                     // during this tile's MFMAs
        const char* Ab = (const char*)As[buf];
        const char* Bb = (const char*)Bs[buf];
#pragma unroll
        for (int ks = 0; ks < 2; ++ks) {
            const int kb = s0 ^ (ks << 6);
            bf16x8 a[4], b[4];
#pragma unroll
            for (int i = 0; i < 4; ++i)
                a[i] = *(const bf16x8*)(Ab + (wr * 64 + i * 16 + frow) * 128 + kb);
#pragma unroll
            for (int n = 0; n < 4; ++n)
                b[n] = *(const bf16x8*)(Bb + (wc * 64 + n * 16 + frow) * 128 + kb);
            __builtin_amdgcn_s_setprio(1);
#pragma unroll
            for (int i = 0; i < 4; ++i)
#pragma unroll
                for (int n = 0; n < 4; ++n)
                    acc[i][n] = __builtin_amdgcn_mfma_f32_16x16x32_bf16(
                        a[i], b[n], acc[i][n], 0, 0, 0);
            __builtin_amdgcn_s_setprio(0);
        }
    }
#undef STAGE

    // epilogue: d2 = sqA + sqB - 2*dot ; out = exp2(c*d2)
    const float cval = c_sh;
    const int q = lane >> 4;
#pragma unroll
    for (int m = 0; m < 4; ++m) {
#pragma unroll
        for (int n = 0; n < 4; ++n) {
            const int col = wc * 64 + n * 16 + frow;
            const float sb = sqB[col];
#pragma unroll
            for (int r = 0; r < 4; ++r) {
                const int row = wr * 64 + m * 16 + q * 4 + r;
                const float d2 = sqA[row] + sb - 2.0f * acc[m][n][r];
                out[(size_t)(i0 + row) * N_ROWS + (j0 + col)] = exp2f(cval * d2);
            }
        }
    }
}

extern "C" void kernel_launch(void* const* d_in, const int* in_sizes, int n_in,
                              void* d_out, int out_size, void* d_ws, size_t ws_size,
                              hipStream_t stream) {
    const float* X = (const float*)d_in[0];
    float* out = (float*)d_out;
    char* ws = (char*)d_ws;

    u16*   Xb   = (u16*)ws;                                   // 4 MB
    float* part = (float*)(ws + (4u << 20));                  // 512 KB
    float* sq   = (float*)(ws + (4u << 20) + (512u << 10));   // 16 KB
    float* prt  = (float*)(ws + (4u << 20) + (512u << 10) + (16u << 10));

    hipLaunchKernelGGL(k_prep, dim3(256), dim3(256), 0, stream, X, Xb, sq, part);
    hipLaunchKernelGGL(k_sigma, dim3(8), dim3(256), 0, stream, sq, part, prt);
    hipLaunchKernelGGL(k_gemm, dim3(1024), dim3(256), 0, stream, Xb, sq, prt, out);
}

// Round 7
// 45.932 us; speedup vs baseline: 1.1622x; 1.0013x over previous
//
#include <hip/hip_runtime.h>
#include <cstdint>

typedef unsigned short u16;
typedef unsigned int u32;
typedef __bf16 bf16x8 __attribute__((ext_vector_type(8)));
typedef float f32x4 __attribute__((ext_vector_type(4)));

#define N_ROWS 4096
#define D_COLS 512

#if __has_builtin(__builtin_amdgcn_exp2f)
#define EXP2(x) __builtin_amdgcn_exp2f(x)
#else
#define EXP2(x) exp2f(x)
#endif

__device__ __forceinline__ u16 f2bf(float f) {
    u32 u = __float_as_uint(f);
    u += 0x7fffu + ((u >> 16) & 1u);
    return (u16)(u >> 16);
}

#define GLDS(g, l)                                                            \
    __builtin_amdgcn_global_load_lds(                                         \
        (const __attribute__((address_space(1))) void*)(g),                   \
        (__attribute__((address_space(3))) void*)(l), 16, 0, 0)

// ---------------- kernel 1: convert + row norms + partial column sums -------
__global__ __launch_bounds__(256) void k_prep(const float* __restrict__ X,
                                              u16* __restrict__ Xb,
                                              float* __restrict__ sq,
                                              float* __restrict__ partial) {
    __shared__ float cs[4][512];
    const int tid = threadIdx.x;
    const int w = tid >> 6, l = tid & 63;
    const int row0 = blockIdx.x * 16 + w * 4;
    float csum[8] = {0.f,0.f,0.f,0.f,0.f,0.f,0.f,0.f};
#pragma unroll
    for (int r = 0; r < 4; ++r) {
        const int row = row0 + r;
        const float4* src = (const float4*)(X + (size_t)row * D_COLS);
        float4 f0 = src[l * 2];
        float4 f1 = src[l * 2 + 1];
        float v[8] = {f0.x, f0.y, f0.z, f0.w, f1.x, f1.y, f1.z, f1.w};
        float ss = 0.f;
#pragma unroll
        for (int j = 0; j < 8; ++j) { ss += v[j] * v[j]; csum[j] += v[j]; }
        uint4 st;
        st.x = (u32)f2bf(v[0]) | ((u32)f2bf(v[1]) << 16);
        st.y = (u32)f2bf(v[2]) | ((u32)f2bf(v[3]) << 16);
        st.z = (u32)f2bf(v[4]) | ((u32)f2bf(v[5]) << 16);
        st.w = (u32)f2bf(v[6]) | ((u32)f2bf(v[7]) << 16);
        *(uint4*)(Xb + (size_t)row * D_COLS + l * 8) = st;
#pragma unroll
        for (int m = 32; m > 0; m >>= 1) ss += __shfl_xor(ss, m, 64);
        if (l == 0) sq[row] = ss;
    }
#pragma unroll
    for (int j = 0; j < 8; ++j) cs[w][l * 8 + j] = csum[j];
    __syncthreads();
    for (int d = tid; d < 512; d += 256)
        partial[blockIdx.x * 512 + d] = cs[0][d] + cs[1][d] + cs[2][d] + cs[3][d];
}

// ---------------- kernel 2: S1/S2 partials, 8 blocks ------------------------
__global__ __launch_bounds__(256) void k_sigma(const float* __restrict__ sq,
                                               const float* __restrict__ partial,
                                               float* __restrict__ parts) {
    __shared__ float csm[4][64];
    __shared__ float red[8];
    const int g = blockIdx.x;
    const int t = threadIdx.x;
    const int c = g * 64 + (t & 63);
    const int ch = t >> 6;
    float cssum = 0.f;
#pragma unroll 8
    for (int b = ch * 64; b < ch * 64 + 64; ++b) cssum += partial[b * 512 + c];
    csm[ch][t & 63] = cssum;
    float s1 = sq[g * 512 + t] + sq[g * 512 + 256 + t];
    __syncthreads();
    float s2 = 0.f;
    if (t < 64) {
        float v = csm[0][t] + csm[1][t] + csm[2][t] + csm[3][t];
        s2 = v * v;
    }
#pragma unroll
    for (int m = 32; m > 0; m >>= 1) {
        s1 += __shfl_xor(s1, m, 64);
        s2 += __shfl_xor(s2, m, 64);
    }
    if ((t & 63) == 0) { red[ch] = s1; red[4 + ch] = s2; }
    __syncthreads();
    if (t == 0) {
        parts[g] = red[0] + red[1] + red[2] + red[3];
        parts[8 + g] = red[4];
    }
}

// ---------------- kernel 3: 128x128 GEMM (R6 loop) + LDS-transpose epilogue -
// 4 waves (2x2), wave tile 64x64, BK=64, 8 K-tiles, 2 blocks/CU, grid 1024.
__global__ __launch_bounds__(256, 2) void k_gemm(const u16* __restrict__ Xb,
                                                 const float* __restrict__ sq,
                                                 const float* __restrict__ parts,
                                                 float* __restrict__ out) {
    __shared__ __align__(16) char pool[65536];      // As[2]|Bs[2]; epilogue tile
    __shared__ float sqA[128], sqB[128];
    __shared__ float c_sh;

    const int tid = threadIdx.x;
    const int lane = tid & 63;
    const int wid = tid >> 6;
    const int wr = wid >> 1, wc = wid & 1;           // 2x2 waves, 64x64 each

    // T1: bijective XCD swizzle — each XCD owns an 8(by) x 16(bx) rect
    const int bid = blockIdx.x;                      // 0..1023
    const int xcd = bid & 7, rr = bid >> 3;          // rr 0..127
    const int by = (xcd >> 1) * 8 + (rr & 7);
    const int bx = (xcd & 1) * 16 + (rr >> 3);
    const int i0 = by * 128, j0 = bx * 128;

    // staging map: T2 swizzle pre-applied on global source; LDS dest linear.
    const int strow = tid >> 3;                      // 0..31
    const int sslot = (tid & 7) ^ (strow & 7);
    const char* xb = (const char*)Xb;
    const char* gA = xb + (size_t)(i0 + strow) * 1024 + sslot * 16;
    const char* gB = xb + (size_t)(j0 + strow) * 1024 + sslot * 16;

#define STAGE(buf, kt)                                                        \
    do {                                                                      \
        _Pragma("unroll")                                                     \
        for (int s = 0; s < 4; ++s) {                                         \
            GLDS(gA + s * 32768 + (kt) * 128,                                 \
                 pool + (buf) * 16384 + s * 4096 + tid * 16);                 \
            GLDS(gB + s * 32768 + (kt) * 128,                                 \
                 pool + 32768 + (buf) * 16384 + s * 4096 + tid * 16);         \
        }                                                                     \
    } while (0)

    // prologue: stage tile 0; sq + c while loads fly
    STAGE(0, 0);
    if (tid < 128) sqA[tid] = sq[i0 + tid];
    else           sqB[tid - 128] = sq[j0 + tid - 128];
    if (tid == 0) {
        float S1 = 0.f, S2 = 0.f;
#pragma unroll
        for (int i = 0; i < 8; ++i) { S1 += parts[i]; S2 += parts[8 + i]; }
        const float mean_d2 = 2.f * S1 / (float)N_ROWS
                            - 2.f * S2 / ((float)N_ROWS * (float)N_ROWS);
        c_sh = -1.4426950408889634f / (2.f * mean_d2);   // ALPHA=1
    }

    f32x4 acc[4][4];
#pragma unroll
    for (int m = 0; m < 4; ++m)
#pragma unroll
        for (int n = 0; n < 4; ++n) acc[m][n] = (f32x4){0.f, 0.f, 0.f, 0.f};

    const int frow = lane & 15;
    const int klane = lane >> 4;
    const int q = lane >> 4;
    const int s0 = (klane ^ (frow & 7)) << 4;        // read-side swizzled slot

    for (int kt = 0; kt < 8; ++kt) {
        const int buf = kt & 1;
        // implicit vmcnt(0)+lgkmcnt(0)+barrier
        __syncthreads();
        if (kt < 7) STAGE(buf ^ 1, kt + 1);
        const char* Ab = pool + buf * 16384;
        const char* Bb = pool + 32768 + buf * 16384;
#pragma unroll
        for (int ks = 0; ks < 2; ++ks) {
            const int kb = s0 ^ (ks << 6);
            bf16x8 a[4], b[4];
#pragma unroll
            for (int i = 0; i < 4; ++i)
                a[i] = *(const bf16x8*)(Ab + (wr * 64 + i * 16 + frow) * 128 + kb);
#pragma unroll
            for (int n = 0; n < 4; ++n)
                b[n] = *(const bf16x8*)(Bb + (wc * 64 + n * 16 + frow) * 128 + kb);
            __builtin_amdgcn_s_setprio(1);
#pragma unroll
            for (int i = 0; i < 4; ++i)
#pragma unroll
                for (int n = 0; n < 4; ++n)
                    acc[i][n] = __builtin_amdgcn_mfma_f32_16x16x32_bf16(
                        a[i], b[n], acc[i][n], 0, 0, 0);
            __builtin_amdgcn_s_setprio(0);
        }
    }
#undef STAGE

    // ---- epilogue: exp2 into LDS [32][132] tile, float4 coalesced stores ---
    __syncthreads();                 // K-loop LDS is dead, safe to overlay
    float (*eps)[132] = (float (*)[132])pool;        // 16.9 KB, overlays As
    const float cval = c_sh;
    const int lrow = tid >> 3;       // 0..31
    const int seg = tid & 7;         // 0..7
#pragma unroll
    for (int m = 0; m < 4; ++m) {
#pragma unroll
        for (int n = 0; n < 4; ++n) {
            const int col = wc * 64 + n * 16 + frow;
            const float sb = sqB[col];
#pragma unroll
            for (int r = 0; r < 4; ++r) {
                const int row = wr * 64 + m * 16 + q * 4 + r;
                const float d2 = sqA[row] + sb - 2.0f * acc[m][n][r];
                eps[wr * 16 + q * 4 + r][col] = EXP2(cval * d2);
            }
        }
        __syncthreads();             // eps tile complete
        const int grow = i0 + (lrow >> 4) * 64 + m * 16 + (lrow & 15);
        float4* orow = (float4*)(out + (size_t)grow * N_ROWS + j0);
        const float* er = eps[lrow];
#pragma unroll
        for (int s = 0; s < 4; ++s) {
            const int f4 = seg + s * 8;
            orow[f4] = *(const float4*)(er + f4 * 4);
        }
        __syncthreads();             // stores read out of eps; safe to rewrite
    }
}

extern "C" void kernel_launch(void* const* d_in, const int* in_sizes, int n_in,
                              void* d_out, int out_size, void* d_ws, size_t ws_size,
                              hipStream_t stream) {
    const float* X = (const float*)d_in[0];
    float* out = (float*)d_out;
    char* ws = (char*)d_ws;

    u16*   Xb   = (u16*)ws;                                   // 4 MB
    float* part = (float*)(ws + (4u << 20));                  // 512 KB
    float* sq   = (float*)(ws + (4u << 20) + (512u << 10));   // 16 KB
    float* prt  = (float*)(ws + (4u << 20) + (512u << 10) + (16u << 10));

    hipLaunchKernelGGL(k_prep, dim3(256), dim3(256), 0, stream, X, Xb, sq, part);
    hipLaunchKernelGGL(k_sigma, dim3(8), dim3(256), 0, stream, sq, part, prt);
    hipLaunchKernelGGL(k_gemm, dim3(1024), dim3(256), 0, stream, Xb, sq, prt, out);
}